// Round 1
// baseline (329.240 us; speedup 1.0000x reference)
//
#include <hip/hip_runtime.h>

// Shapes: B=16, S=1024, E=64, H=8, d=8, INPUT_DIM=310
// local mask: |i-j|<=5  (11 keys); sparse mask: j%3==0 or i==j (342 keys + maybe diag)

#define INV_SQRT8 0.3535533905932738f

__device__ __forceinline__ float4 ld4(const float* p) { return *(const float4*)p; }

__device__ __forceinline__ float4 f4fma(float s, float4 w, float4 a) {
  a.x = fmaf(s, w.x, a.x); a.y = fmaf(s, w.y, a.y);
  a.z = fmaf(s, w.z, a.z); a.w = fmaf(s, w.w, a.w);
  return a;
}

// ---------------- Generic small-N GEMM: C[r, coff+n] = A[r,:K] . W[n,:K] + bias[n]
// Block tile 64x64, thread tile 4x4, K-chunks of 64, LDS pad 68 (bank-conflict free,
// float4-aligned).
#define BM 64
#define BN 64
#define KCH 64
#define AST 68
#define WST 68

__global__ __launch_bounds__(256) void gemm_bias(
    const float* __restrict__ A, int lda,
    const float* __restrict__ W, int K,
    const float* __restrict__ bias,
    float* __restrict__ C, int ldc, int coff)
{
  __shared__ __align__(16) float As[BM * AST];
  __shared__ __align__(16) float Ws[KCH * WST];
  const int tid  = threadIdx.x;
  const int row0 = blockIdx.x * BM;
  const int col0 = blockIdx.y * BN;
  const int tcol = (tid & 15) * 4;
  const int trow = (tid >> 4) * 4;

  float4 acc[4];
  acc[0] = make_float4(0.f, 0.f, 0.f, 0.f);
  acc[1] = make_float4(0.f, 0.f, 0.f, 0.f);
  acc[2] = make_float4(0.f, 0.f, 0.f, 0.f);
  acc[3] = make_float4(0.f, 0.f, 0.f, 0.f);

  for (int k0 = 0; k0 < K; k0 += KCH) {
    for (int idx = tid; idx < BM * KCH; idx += 256) {
      int r = idx >> 6, k = idx & 63, gk = k0 + k;
      As[r * AST + k] = (gk < K) ? A[(size_t)(row0 + r) * lda + gk] : 0.f;
    }
    for (int idx = tid; idx < BN * KCH; idx += 256) {
      int n = idx >> 6, k = idx & 63, gk = k0 + k;
      Ws[k * WST + n] = (gk < K) ? W[(size_t)(col0 + n) * K + gk] : 0.f;
    }
    __syncthreads();
    #pragma unroll
    for (int kk = 0; kk < KCH; kk += 4) {
      float4 w0 = ld4(&Ws[(kk + 0) * WST + tcol]);
      float4 w1 = ld4(&Ws[(kk + 1) * WST + tcol]);
      float4 w2 = ld4(&Ws[(kk + 2) * WST + tcol]);
      float4 w3 = ld4(&Ws[(kk + 3) * WST + tcol]);
      #pragma unroll
      for (int i = 0; i < 4; i++) {
        float4 a = ld4(&As[(trow + i) * AST + kk]);
        acc[i] = f4fma(a.x, w0, acc[i]);
        acc[i] = f4fma(a.y, w1, acc[i]);
        acc[i] = f4fma(a.z, w2, acc[i]);
        acc[i] = f4fma(a.w, w3, acc[i]);
      }
    }
    __syncthreads();
  }
  float4 bv = ld4(&bias[col0 + tcol]);
  #pragma unroll
  for (int i = 0; i < 4; i++) {
    float4 o;
    o.x = acc[i].x + bv.x; o.y = acc[i].y + bv.y;
    o.z = acc[i].z + bv.z; o.w = acc[i].w + bv.w;
    *(float4*)&C[(size_t)(row0 + trow + i) * ldc + coff + col0 + tcol] = o;
  }
}

// ---------------- Local attention: thread per (b,i,h), 11-key window.
// qkv layout [B*S][192]: q=0..63, k=64..127, v=128..191; head h -> dims h*8..h*8+7
__global__ __launch_bounds__(256) void local_attn(
    const float* __restrict__ qkv, float* __restrict__ o)
{
  int t = blockIdx.x * 256 + threadIdx.x;   // B*S*H = 131072
  int h = t & 7;
  int i = (t >> 3) & 1023;
  int b = t >> 13;
  const float* base = qkv + (size_t)b * 1024 * 192;
  const float* qp = base + (size_t)i * 192 + h * 8;
  float4 q0 = ld4(qp), q1 = ld4(qp + 4);
  float l = 0.f;
  float4 o0 = make_float4(0.f, 0.f, 0.f, 0.f);
  float4 o1 = make_float4(0.f, 0.f, 0.f, 0.f);
  int jlo = i - 5; if (jlo < 0) jlo = 0;
  int jhi = i + 5; if (jhi > 1023) jhi = 1023;
  for (int j = jlo; j <= jhi; j++) {
    const float* kp = base + (size_t)j * 192 + 64 + h * 8;
    float4 k0 = ld4(kp), k1 = ld4(kp + 4);
    float s = q0.x * k0.x + q0.y * k0.y + q0.z * k0.z + q0.w * k0.w
            + q1.x * k1.x + q1.y * k1.y + q1.z * k1.z + q1.w * k1.w;
    float p = __expf(s * INV_SQRT8);
    l += p;
    float4 v0 = ld4(kp + 64), v1 = ld4(kp + 68);
    o0 = f4fma(p, v0, o0);
    o1 = f4fma(p, v1, o1);
  }
  float inv = 1.f / l;
  float* op = o + (size_t)(b * 1024 + i) * 64 + h * 8;
  float4 r0, r1;
  r0.x = o0.x * inv; r0.y = o0.y * inv; r0.z = o0.z * inv; r0.w = o0.w * inv;
  r1.x = o1.x * inv; r1.y = o1.y * inv; r1.z = o1.z * inv; r1.w = o1.w * inv;
  *(float4*)op = r0;
  *(float4*)(op + 4) = r1;
}

// ---------------- Global (sparse) attention: block per (b,h,qtile of 256),
// compressed K/V (j = 0,3,...,1023 -> 342 keys) staged in LDS; per-key LDS
// broadcast reads; diagonal handled separately when i%3 != 0.
#define NKEY 342
__global__ __launch_bounds__(256) void global_attn(
    const float* __restrict__ qkv, float* __restrict__ o)
{
  __shared__ __align__(16) float Ks[NKEY * 8];
  __shared__ __align__(16) float Vs[NKEY * 8];
  int bh = blockIdx.x >> 2;
  int qt = blockIdx.x & 3;
  int b = bh >> 3, h = bh & 7;
  const float* base = qkv + (size_t)b * 1024 * 192;
  for (int idx = threadIdx.x; idx < NKEY * 8; idx += 256) {
    int kk = idx >> 3, d = idx & 7;
    const float* row = base + (size_t)(kk * 3) * 192 + 64 + h * 8;
    Ks[idx] = row[d];
    Vs[idx] = row[64 + d];
  }
  __syncthreads();
  int i = qt * 256 + threadIdx.x;
  const float* qp = base + (size_t)i * 192 + h * 8;
  float4 q0 = ld4(qp), q1 = ld4(qp + 4);
  float l = 0.f;
  float4 o0 = make_float4(0.f, 0.f, 0.f, 0.f);
  float4 o1 = make_float4(0.f, 0.f, 0.f, 0.f);
  #pragma unroll 2
  for (int kk = 0; kk < NKEY; kk++) {
    float4 k0 = ld4(&Ks[kk * 8]), k1 = ld4(&Ks[kk * 8 + 4]);
    float s = q0.x * k0.x + q0.y * k0.y + q0.z * k0.z + q0.w * k0.w
            + q1.x * k1.x + q1.y * k1.y + q1.z * k1.z + q1.w * k1.w;
    float p = __expf(s * INV_SQRT8);
    l += p;
    float4 v0 = ld4(&Vs[kk * 8]), v1 = ld4(&Vs[kk * 8 + 4]);
    o0 = f4fma(p, v0, o0);
    o1 = f4fma(p, v1, o1);
  }
  if (i % 3 != 0) {   // diagonal key not in the j%3==0 set
    const float* kp = base + (size_t)i * 192 + 64 + h * 8;
    float4 k0 = ld4(kp), k1 = ld4(kp + 4);
    float s = q0.x * k0.x + q0.y * k0.y + q0.z * k0.z + q0.w * k0.w
            + q1.x * k1.x + q1.y * k1.y + q1.z * k1.z + q1.w * k1.w;
    float p = __expf(s * INV_SQRT8);
    l += p;
    float4 v0 = ld4(kp + 64), v1 = ld4(kp + 68);
    o0 = f4fma(p, v0, o0);
    o1 = f4fma(p, v1, o1);
  }
  float inv = 1.f / l;
  float* op = o + (size_t)(b * 1024 + i) * 64 + h * 8;
  float4 r0, r1;
  r0.x = o0.x * inv; r0.y = o0.y * inv; r0.z = o0.z * inv; r0.w = o0.w * inv;
  r1.x = o1.x * inv; r1.y = o1.y * inv; r1.z = o1.z * inv; r1.w = o1.w * inv;
  *(float4*)op = r0;
  *(float4*)(op + 4) = r1;
}

// ---------------- Pool scores: thread per row, sc = tanh(f.Pw1^T+b1).Pw2^T+b2
__global__ __launch_bounds__(256) void score_kernel(
    const float* __restrict__ fused,
    const float* __restrict__ pw1, const float* __restrict__ pb1,
    const float* __restrict__ pw2, const float* __restrict__ pb2,
    float* __restrict__ scores)
{
  int r = blockIdx.x * 256 + threadIdx.x;   // 16384 rows
  const float* f = fused + (size_t)r * 64;
  float4 fr[16];
  #pragma unroll
  for (int e = 0; e < 16; e++) fr[e] = ld4(f + e * 4);
  float sc = pb2[0];
  #pragma unroll 4
  for (int j = 0; j < 32; j++) {
    const float* wr = pw1 + j * 64;
    float hj = pb1[j];
    #pragma unroll
    for (int e = 0; e < 16; e++) {
      float4 w = ld4(wr + e * 4);
      hj += fr[e].x * w.x + fr[e].y * w.y + fr[e].z * w.z + fr[e].w * w.w;
    }
    sc += tanhf(hj) * pw2[j];
  }
  scores[r] = sc;
}

// ---------------- Softmax over S (per b) + weighted sum -> out[b][64]
__global__ __launch_bounds__(1024) void pool_kernel(
    const float* __restrict__ fused, const float* __restrict__ scores,
    float* __restrict__ out)
{
  __shared__ float pbuf[1024];
  __shared__ float part[1024];
  __shared__ float red[20];
  int b = blockIdx.x, t = threadIdx.x;
  float sc = scores[b * 1024 + t];
  float m = sc;
  #pragma unroll
  for (int off = 32; off > 0; off >>= 1)
    m = fmaxf(m, __shfl_xor(m, off, 64));
  int wid = t >> 6, lane = t & 63;
  if (lane == 0) red[wid] = m;
  __syncthreads();
  if (t == 0) {
    float mm = red[0];
    for (int g = 1; g < 16; g++) mm = fmaxf(mm, red[g]);
    red[16] = mm;
  }
  __syncthreads();
  m = red[16];
  float p = __expf(sc - m);
  pbuf[t] = p;
  float ss = p;
  #pragma unroll
  for (int off = 32; off > 0; off >>= 1)
    ss += __shfl_xor(ss, off, 64);
  if (lane == 0) red[wid] = ss;
  __syncthreads();
  if (t == 0) {
    float s2 = 0.f;
    for (int g = 0; g < 16; g++) s2 += red[g];
    red[17] = 1.f / s2;
  }
  __syncthreads();
  float inv = red[17];
  int e = t & 63, g = t >> 6;
  float acc = 0.f;
  for (int s = g; s < 1024; s += 16)
    acc = fmaf(pbuf[s], fused[((size_t)b * 1024 + s) * 64 + e], acc);
  part[t] = acc;
  __syncthreads();
  if (t < 64) {
    float tot = 0.f;
    for (int g2 = 0; g2 < 16; g2++) tot += part[g2 * 64 + t];
    out[b * 64 + t] = tot * inv;
  }
}

extern "C" void kernel_launch(void* const* d_in, const int* in_sizes, int n_in,
                              void* d_out, int out_size, void* d_ws, size_t ws_size,
                              hipStream_t stream)
{
  const float* x          = (const float*)d_in[0];
  const float* proj_w     = (const float*)d_in[1];
  const float* proj_b     = (const float*)d_in[2];
  const float* loc_in_w   = (const float*)d_in[3];
  const float* loc_in_b   = (const float*)d_in[4];
  const float* loc_out_w  = (const float*)d_in[5];
  const float* loc_out_b  = (const float*)d_in[6];
  const float* glob_in_w  = (const float*)d_in[7];
  const float* glob_in_b  = (const float*)d_in[8];
  const float* glob_out_w = (const float*)d_in[9];
  const float* glob_out_b = (const float*)d_in[10];
  const float* fusion_w   = (const float*)d_in[11];
  const float* fusion_b   = (const float*)d_in[12];
  const float* pw1        = (const float*)d_in[13];
  const float* pb1        = (const float*)d_in[14];
  const float* pw2        = (const float*)d_in[15];
  const float* pb2        = (const float*)d_in[16];

  float* ws     = (float*)d_ws;
  float* xp     = ws;                 // [16384,64]  (reused as FUSED later)
  float* qkv_l  = ws + 1048576;       // [16384,192]
  float* qkv_g  = ws + 4194304;       // [16384,192]
  float* o_l    = ws + 7340032;       // [16384,64]
  float* o_g    = ws + 8388608;       // [16384,64]
  float* cat    = ws + 9437184;       // [16384,128]
  float* scores = ws + 11534336;      // [16384]
  float* fused  = xp;
  float* out    = (float*)d_out;

  dim3 blk(256);
  // xp = x @ proj_w^T + proj_b      (M=16384,K=310,N=64)
  gemm_bias<<<dim3(256, 1), blk, 0, stream>>>(x, 310, proj_w, 310, proj_b, xp, 64, 0);
  // qkv = xp @ in_w^T + in_b        (K=64, N=192) x2
  gemm_bias<<<dim3(256, 3), blk, 0, stream>>>(xp, 64, loc_in_w, 64, loc_in_b, qkv_l, 192, 0);
  gemm_bias<<<dim3(256, 3), blk, 0, stream>>>(xp, 64, glob_in_w, 64, glob_in_b, qkv_g, 192, 0);
  // attention branches
  local_attn<<<512, blk, 0, stream>>>(qkv_l, o_l);
  global_attn<<<512, blk, 0, stream>>>(qkv_g, o_g);
  // out-projections into concat buffer
  gemm_bias<<<dim3(256, 1), blk, 0, stream>>>(o_l, 64, loc_out_w, 64, loc_out_b, cat, 128, 0);
  gemm_bias<<<dim3(256, 1), blk, 0, stream>>>(o_g, 64, glob_out_w, 64, glob_out_b, cat, 128, 64);
  // fused = cat @ fusion_w^T + fusion_b   (K=128,N=64)
  gemm_bias<<<dim3(256, 1), blk, 0, stream>>>(cat, 128, fusion_w, 128, fusion_b, fused, 64, 0);
  // pooling
  score_kernel<<<64, blk, 0, stream>>>(fused, pw1, pb1, pw2, pb2, scores);
  pool_kernel<<<16, dim3(1024), 0, stream>>>(fused, scores, out);
}

// Round 2
// 280.829 us; speedup vs baseline: 1.1724x; 1.1724x over previous
//
#include <hip/hip_runtime.h>

// Shapes: B=16, S=1024, E=64, H=8, d=8, INPUT_DIM=310
// local mask: |i-j|<=5 (11 keys); sparse mask: j%3==0 or i==j (342 keys + maybe diag)

#define INV_SQRT8 0.3535533905932738f

__device__ __forceinline__ float4 ld4(const float* p) { return *(const float4*)p; }

__device__ __forceinline__ float4 f4fma(float s, float4 w, float4 a) {
  a.x = fmaf(s, w.x, a.x); a.y = fmaf(s, w.y, a.y);
  a.z = fmaf(s, w.z, a.z); a.w = fmaf(s, w.w, a.w);
  return a;
}

// ---------------- GEMM: C[r, coff+n] = A[r,:K] . W[n,:K] + bias[n]
// BM=32, BN=64, 256 threads, 2x4 thread-tile. 26KB LDS -> 6 blocks/CU cap;
// grid >= 512 gives >=2 blocks/CU (8 waves/CU) so cross-block overlap hides
// staging latency. blockIdx.z selects between two (A,W,bias,C,coff) sets so
// independent GEMMs share one launch.
#define BM 32
#define BN 64
#define AST 68
#define WST 68

__global__ __launch_bounds__(256) void gemm_bias(
    const float* __restrict__ A0, const float* __restrict__ A1,
    const float* __restrict__ W0, const float* __restrict__ W1,
    const float* __restrict__ b0, const float* __restrict__ b1,
    float* __restrict__ C0, float* __restrict__ C1,
    int lda, int K, int ldc, int coff0, int coff1)
{
  __shared__ __align__(16) float As[BM * AST];
  __shared__ __align__(16) float Ws[64 * WST];

  const int z = blockIdx.z;
  const float* A = z ? A1 : A0;
  const float* W = z ? W1 : W0;
  const float* bias = z ? b1 : b0;
  float* C = z ? C1 : C0;
  const int coff = z ? coff1 : coff0;

  const int tid  = threadIdx.x;
  const int row0 = blockIdx.x * BM;
  const int col0 = blockIdx.y * BN;
  const int tcol = (tid & 15) * 4;
  const int trow = (tid >> 4) * 2;
  const bool vec = ((lda & 3) == 0) && ((K & 63) == 0);

  float4 acc[2];
  acc[0] = make_float4(0.f, 0.f, 0.f, 0.f);
  acc[1] = make_float4(0.f, 0.f, 0.f, 0.f);

  for (int k0 = 0; k0 < K; k0 += 64) {
    if (vec) {
      // A tile: 32x64 = 512 float4, 2 per thread
      #pragma unroll
      for (int ii = 0; ii < 2; ii++) {
        int idx = tid + ii * 256;
        int r = idx >> 4, k4 = (idx & 15) * 4;
        *(float4*)&As[r * AST + k4] = ld4(&A[(size_t)(row0 + r) * lda + k0 + k4]);
      }
      // W tile: 64x64 = 1024 float4, 4 per thread, transposed into LDS
      #pragma unroll
      for (int ii = 0; ii < 4; ii++) {
        int idx = tid + ii * 256;
        int n = idx >> 4, k4 = (idx & 15) * 4;
        float4 w = ld4(&W[(size_t)(col0 + n) * K + k0 + k4]);
        Ws[(k4 + 0) * WST + n] = w.x;
        Ws[(k4 + 1) * WST + n] = w.y;
        Ws[(k4 + 2) * WST + n] = w.z;
        Ws[(k4 + 3) * WST + n] = w.w;
      }
    } else {
      for (int idx = tid; idx < BM * 64; idx += 256) {
        int r = idx >> 6, k = idx & 63, gk = k0 + k;
        As[r * AST + k] = (gk < K) ? A[(size_t)(row0 + r) * lda + gk] : 0.f;
      }
      for (int idx = tid; idx < BN * 64; idx += 256) {
        int n = idx >> 6, k = idx & 63, gk = k0 + k;
        Ws[k * WST + n] = (gk < K) ? W[(size_t)(col0 + n) * K + gk] : 0.f;
      }
    }
    __syncthreads();
    #pragma unroll
    for (int kk = 0; kk < 64; kk += 4) {
      float4 w0 = ld4(&Ws[(kk + 0) * WST + tcol]);
      float4 w1 = ld4(&Ws[(kk + 1) * WST + tcol]);
      float4 w2 = ld4(&Ws[(kk + 2) * WST + tcol]);
      float4 w3 = ld4(&Ws[(kk + 3) * WST + tcol]);
      #pragma unroll
      for (int i = 0; i < 2; i++) {
        float4 a = ld4(&As[(trow + i) * AST + kk]);
        acc[i] = f4fma(a.x, w0, acc[i]);
        acc[i] = f4fma(a.y, w1, acc[i]);
        acc[i] = f4fma(a.z, w2, acc[i]);
        acc[i] = f4fma(a.w, w3, acc[i]);
      }
    }
    __syncthreads();
  }
  float4 bv = ld4(&bias[col0 + tcol]);
  #pragma unroll
  for (int i = 0; i < 2; i++) {
    float4 o;
    o.x = acc[i].x + bv.x; o.y = acc[i].y + bv.y;
    o.z = acc[i].z + bv.z; o.w = acc[i].w + bv.w;
    *(float4*)&C[(size_t)(row0 + trow + i) * ldc + coff + col0 + tcol] = o;
  }
}

// ---------------- Local attention: thread per (b,i,h), 11-key window.
// qkv layout [B*S][192]: q=0..63, k=64..127, v=128..191; head h -> dims h*8..h*8+7
__global__ __launch_bounds__(256) void local_attn(
    const float* __restrict__ qkv, float* __restrict__ o)
{
  int t = blockIdx.x * 256 + threadIdx.x;   // B*S*H = 131072
  int h = t & 7;
  int i = (t >> 3) & 1023;
  int b = t >> 13;
  const float* base = qkv + (size_t)b * 1024 * 192;
  const float* qp = base + (size_t)i * 192 + h * 8;
  float4 q0 = ld4(qp), q1 = ld4(qp + 4);
  float l = 0.f;
  float4 o0 = make_float4(0.f, 0.f, 0.f, 0.f);
  float4 o1 = make_float4(0.f, 0.f, 0.f, 0.f);
  int jlo = i - 5; if (jlo < 0) jlo = 0;
  int jhi = i + 5; if (jhi > 1023) jhi = 1023;
  for (int j = jlo; j <= jhi; j++) {
    const float* kp = base + (size_t)j * 192 + 64 + h * 8;
    float4 k0 = ld4(kp), k1 = ld4(kp + 4);
    float s = q0.x * k0.x + q0.y * k0.y + q0.z * k0.z + q0.w * k0.w
            + q1.x * k1.x + q1.y * k1.y + q1.z * k1.z + q1.w * k1.w;
    float p = __expf(s * INV_SQRT8);
    l += p;
    float4 v0 = ld4(kp + 64), v1 = ld4(kp + 68);
    o0 = f4fma(p, v0, o0);
    o1 = f4fma(p, v1, o1);
  }
  float inv = 1.f / l;
  float* op = o + (size_t)(b * 1024 + i) * 64 + h * 8;
  float4 r0, r1;
  r0.x = o0.x * inv; r0.y = o0.y * inv; r0.z = o0.z * inv; r0.w = o0.w * inv;
  r1.x = o1.x * inv; r1.y = o1.y * inv; r1.z = o1.z * inv; r1.w = o1.w * inv;
  *(float4*)op = r0;
  *(float4*)(op + 4) = r1;
}

// ---------------- Global (sparse) attention: block per (b,h,half), 256 thr,
// 2 queries per thread (shares every K/V LDS read across 2 queries).
#define NKEY 342
__global__ __launch_bounds__(256) void global_attn(
    const float* __restrict__ qkv, float* __restrict__ o)
{
  __shared__ __align__(16) float Ks[NKEY * 8];
  __shared__ __align__(16) float Vs[NKEY * 8];
  int b = blockIdx.x, h = blockIdx.y, half = blockIdx.z;
  const float* base = qkv + (size_t)b * 1024 * 192;
  for (int idx = threadIdx.x; idx < NKEY * 8; idx += 256) {
    int kk = idx >> 3, d = idx & 7;
    const float* row = base + (size_t)(kk * 3) * 192 + 64 + h * 8;
    Ks[idx] = row[d];
    Vs[idx] = row[64 + d];
  }
  __syncthreads();
  int i0 = half * 512 + threadIdx.x;
  int i1 = i0 + 256;
  const float* qp0 = base + (size_t)i0 * 192 + h * 8;
  const float* qp1 = base + (size_t)i1 * 192 + h * 8;
  float4 qa0 = ld4(qp0), qa1 = ld4(qp0 + 4);
  float4 qb0 = ld4(qp1), qb1 = ld4(qp1 + 4);
  float la = 0.f, lb = 0.f;
  float4 oa0 = make_float4(0.f,0.f,0.f,0.f), oa1 = make_float4(0.f,0.f,0.f,0.f);
  float4 ob0 = make_float4(0.f,0.f,0.f,0.f), ob1 = make_float4(0.f,0.f,0.f,0.f);
  for (int kk = 0; kk < NKEY; kk++) {
    float4 k0 = ld4(&Ks[kk * 8]), k1 = ld4(&Ks[kk * 8 + 4]);
    float sa = qa0.x*k0.x + qa0.y*k0.y + qa0.z*k0.z + qa0.w*k0.w
             + qa1.x*k1.x + qa1.y*k1.y + qa1.z*k1.z + qa1.w*k1.w;
    float sb = qb0.x*k0.x + qb0.y*k0.y + qb0.z*k0.z + qb0.w*k0.w
             + qb1.x*k1.x + qb1.y*k1.y + qb1.z*k1.z + qb1.w*k1.w;
    float pa = __expf(sa * INV_SQRT8);
    float pb = __expf(sb * INV_SQRT8);
    la += pa; lb += pb;
    float4 v0 = ld4(&Vs[kk * 8]), v1 = ld4(&Vs[kk * 8 + 4]);
    oa0 = f4fma(pa, v0, oa0); oa1 = f4fma(pa, v1, oa1);
    ob0 = f4fma(pb, v0, ob0); ob1 = f4fma(pb, v1, ob1);
  }
  // diagonal keys not in the j%3==0 set
  if (i0 % 3 != 0) {
    const float* kp = base + (size_t)i0 * 192 + 64 + h * 8;
    float4 k0 = ld4(kp), k1 = ld4(kp + 4);
    float s = qa0.x*k0.x + qa0.y*k0.y + qa0.z*k0.z + qa0.w*k0.w
            + qa1.x*k1.x + qa1.y*k1.y + qa1.z*k1.z + qa1.w*k1.w;
    float p = __expf(s * INV_SQRT8);
    la += p;
    float4 v0 = ld4(kp + 64), v1 = ld4(kp + 68);
    oa0 = f4fma(p, v0, oa0); oa1 = f4fma(p, v1, oa1);
  }
  if (i1 % 3 != 0) {
    const float* kp = base + (size_t)i1 * 192 + 64 + h * 8;
    float4 k0 = ld4(kp), k1 = ld4(kp + 4);
    float s = qb0.x*k0.x + qb0.y*k0.y + qb0.z*k0.z + qb0.w*k0.w
            + qb1.x*k1.x + qb1.y*k1.y + qb1.z*k1.z + qb1.w*k1.w;
    float p = __expf(s * INV_SQRT8);
    lb += p;
    float4 v0 = ld4(kp + 64), v1 = ld4(kp + 68);
    ob0 = f4fma(p, v0, ob0); ob1 = f4fma(p, v1, ob1);
  }
  float inva = 1.f / la, invb = 1.f / lb;
  float* opa = o + (size_t)(b * 1024 + i0) * 64 + h * 8;
  float* opb = o + (size_t)(b * 1024 + i1) * 64 + h * 8;
  float4 r;
  r.x = oa0.x*inva; r.y = oa0.y*inva; r.z = oa0.z*inva; r.w = oa0.w*inva; *(float4*)opa = r;
  r.x = oa1.x*inva; r.y = oa1.y*inva; r.z = oa1.z*inva; r.w = oa1.w*inva; *(float4*)(opa+4) = r;
  r.x = ob0.x*invb; r.y = ob0.y*invb; r.z = ob0.z*invb; r.w = ob0.w*invb; *(float4*)opb = r;
  r.x = ob1.x*invb; r.y = ob1.y*invb; r.z = ob1.z*invb; r.w = ob1.w*invb; *(float4*)(opb+4) = r;
}

// ---------------- Pool scores: thread per row (64-thr blocks, grid 256)
__global__ __launch_bounds__(64) void score_kernel(
    const float* __restrict__ fused,
    const float* __restrict__ pw1, const float* __restrict__ pb1,
    const float* __restrict__ pw2, const float* __restrict__ pb2,
    float* __restrict__ scores)
{
  int r = blockIdx.x * 64 + threadIdx.x;   // 16384 rows
  const float* f = fused + (size_t)r * 64;
  float4 fr[16];
  #pragma unroll
  for (int e = 0; e < 16; e++) fr[e] = ld4(f + e * 4);
  float sc = pb2[0];
  #pragma unroll 4
  for (int j = 0; j < 32; j++) {
    const float* wr = pw1 + j * 64;
    float hj = pb1[j];
    #pragma unroll
    for (int e = 0; e < 16; e++) {
      float4 w = ld4(wr + e * 4);
      hj += fr[e].x * w.x + fr[e].y * w.y + fr[e].z * w.z + fr[e].w * w.w;
    }
    sc += tanhf(hj) * pw2[j];
  }
  scores[r] = sc;
}

// ---------------- Softmax over S (per b) + weighted sum -> out[b][64]
__global__ __launch_bounds__(1024) void pool_kernel(
    const float* __restrict__ fused, const float* __restrict__ scores,
    float* __restrict__ out)
{
  __shared__ float pbuf[1024];
  __shared__ float part[1024];
  __shared__ float red[20];
  int b = blockIdx.x, t = threadIdx.x;
  float sc = scores[b * 1024 + t];
  float m = sc;
  #pragma unroll
  for (int off = 32; off > 0; off >>= 1)
    m = fmaxf(m, __shfl_xor(m, off, 64));
  int wid = t >> 6, lane = t & 63;
  if (lane == 0) red[wid] = m;
  __syncthreads();
  if (t == 0) {
    float mm = red[0];
    for (int g = 1; g < 16; g++) mm = fmaxf(mm, red[g]);
    red[16] = mm;
  }
  __syncthreads();
  m = red[16];
  float p = __expf(sc - m);
  pbuf[t] = p;
  float ss = p;
  #pragma unroll
  for (int off = 32; off > 0; off >>= 1)
    ss += __shfl_xor(ss, off, 64);
  if (lane == 0) red[wid] = ss;
  __syncthreads();
  if (t == 0) {
    float s2 = 0.f;
    for (int g = 0; g < 16; g++) s2 += red[g];
    red[17] = 1.f / s2;
  }
  __syncthreads();
  float inv = red[17];
  int e = t & 63, g = t >> 6;
  float acc = 0.f;
  for (int s = g; s < 1024; s += 16)
    acc = fmaf(pbuf[s], fused[((size_t)b * 1024 + s) * 64 + e], acc);
  part[t] = acc;
  __syncthreads();
  if (t < 64) {
    float tot = 0.f;
    for (int g2 = 0; g2 < 16; g2++) tot += part[g2 * 64 + t];
    out[b * 64 + t] = tot * inv;
  }
}

extern "C" void kernel_launch(void* const* d_in, const int* in_sizes, int n_in,
                              void* d_out, int out_size, void* d_ws, size_t ws_size,
                              hipStream_t stream)
{
  const float* x          = (const float*)d_in[0];
  const float* proj_w     = (const float*)d_in[1];
  const float* proj_b     = (const float*)d_in[2];
  const float* loc_in_w   = (const float*)d_in[3];
  const float* loc_in_b   = (const float*)d_in[4];
  const float* loc_out_w  = (const float*)d_in[5];
  const float* loc_out_b  = (const float*)d_in[6];
  const float* glob_in_w  = (const float*)d_in[7];
  const float* glob_in_b  = (const float*)d_in[8];
  const float* glob_out_w = (const float*)d_in[9];
  const float* glob_out_b = (const float*)d_in[10];
  const float* fusion_w   = (const float*)d_in[11];
  const float* fusion_b   = (const float*)d_in[12];
  const float* pw1        = (const float*)d_in[13];
  const float* pb1        = (const float*)d_in[14];
  const float* pw2        = (const float*)d_in[15];
  const float* pb2        = (const float*)d_in[16];

  float* ws     = (float*)d_ws;
  float* xp     = ws;                 // [16384,64]  (reused as FUSED later)
  float* qkv_l  = ws + 1048576;       // [16384,192]
  float* qkv_g  = ws + 4194304;       // [16384,192]
  float* o_l    = ws + 7340032;       // [16384,64]
  float* o_g    = ws + 8388608;       // [16384,64]
  float* cat    = ws + 9437184;       // [16384,128]
  float* scores = ws + 11534336;      // [16384]
  float* fused  = xp;
  float* out    = (float*)d_out;

  dim3 blk(256);
  // xp = x @ proj_w^T + proj_b      (M=16384,K=310,N=64), grid 512
  gemm_bias<<<dim3(512, 1, 1), blk, 0, stream>>>(
      x, x, proj_w, proj_w, proj_b, proj_b, xp, xp, 310, 310, 64, 0, 0);
  // qkv (both branches merged): (512,3,2)
  gemm_bias<<<dim3(512, 3, 2), blk, 0, stream>>>(
      xp, xp, loc_in_w, glob_in_w, loc_in_b, glob_in_b, qkv_l, qkv_g,
      64, 64, 192, 0, 0);
  // attention branches
  local_attn<<<512, blk, 0, stream>>>(qkv_l, o_l);
  global_attn<<<dim3(16, 8, 2), blk, 0, stream>>>(qkv_g, o_g);
  // out-projections merged into concat buffer: (512,1,2)
  gemm_bias<<<dim3(512, 1, 2), blk, 0, stream>>>(
      o_l, o_g, loc_out_w, glob_out_w, loc_out_b, glob_out_b, cat, cat,
      64, 64, 128, 0, 64);
  // fused = cat @ fusion_w^T + fusion_b   (K=128,N=64), grid 512
  gemm_bias<<<dim3(512, 1, 1), blk, 0, stream>>>(
      cat, cat, fusion_w, fusion_w, fusion_b, fusion_b, fused, fused,
      128, 128, 64, 0, 0);
  // pooling
  score_kernel<<<256, dim3(64), 0, stream>>>(fused, pw1, pb1, pw2, pb2, scores);
  pool_kernel<<<16, dim3(1024), 0, stream>>>(fused, scores, out);
}